// Round 12
// baseline (127.207 us; speedup 1.0000x reference)
//
#include <hip/hip_runtime.h>
#include <cfloat>
#include <math.h>

#define D_IN 128
#define D_OUT 64
#define NEG_SLOPE 0.2f
#define ROWH 128  // ushorts per hkv row: 64 fp16 (hk) + 64 bf16 (hv) = 256 B
#define SQRT_LOG2E 1.2011224087864498f

typedef _Float16 half2v __attribute__((ext_vector_type(2)));
typedef _Float16 half8 __attribute__((ext_vector_type(8)));
typedef float f32x4 __attribute__((ext_vector_type(4)));

// pack/unpack helpers ---------------------------------------------------------
__device__ __forceinline__ unsigned short f2bf(float x) {
  union { float f; unsigned u; } a; a.f = x;
  unsigned r = a.u + 0x7FFFu + ((a.u >> 16) & 1u);
  return (unsigned short)(r >> 16);
}
__device__ __forceinline__ unsigned short f2h(float x) {
  union { _Float16 h; unsigned short u; } c;
  c.h = (_Float16)x;  // RNE
  return c.u;
}
__device__ __forceinline__ float4 unpack_bf4(uint2 q) {
  union { unsigned u; float f; } t;
  float4 r;
  t.u = q.x << 16;          r.x = t.f;
  t.u = q.x & 0xFFFF0000u;  r.y = t.f;
  t.u = q.y << 16;          r.z = t.f;
  t.u = q.y & 0xFFFF0000u;  r.w = t.f;
  return r;
}
// fp16-pair dot with f32 accumulate via v_dot2_f32_f16
__device__ __forceinline__ float hdot4(uint2 a, uint2 b) {
  union { unsigned u; half2v h; } al, ah, bl, bh;
  al.u = a.x; ah.u = a.y; bl.u = b.x; bh.u = b.y;
#if __has_builtin(__builtin_amdgcn_fdot2)
  return __builtin_amdgcn_fdot2(al.h, bl.h,
         __builtin_amdgcn_fdot2(ah.h, bh.h, 0.f, false), false);
#else
  return (float)al.h[0] * (float)bl.h[0] + (float)al.h[1] * (float)bl.h[1] +
         (float)ah.h[0] * (float)bh.h[0] + (float)ah.h[1] * (float)bh.h[1];
#endif
}

// ---------------------------------------------------------------------------
// Kernel P: pack W (f32) into per-lane MFMA B-fragments (fp16).
// Wk pre-scaled by sqrt(log2 e) so gathered score dots land in exp2 domain.
// idx < 1024: Wk table; idx >= 1024: Wv table. 2048 entries x 16 B = 32 KB.
// ---------------------------------------------------------------------------
__global__ void bfrag_kernel(const float* __restrict__ Wk,
                             const float* __restrict__ Wv,
                             _Float16* __restrict__ bfrag) {
  const int idx = blockIdx.x * 256 + threadIdx.x;
  if (idx >= 2048) return;
  const int which = idx >> 10;
  const float* __restrict__ W = which ? Wv : Wk;
  const float scale = which ? 1.0f : SQRT_LOG2E;
  const int li = idx & 1023;
  const int lane = li & 63;
  const int nt = (li >> 6) & 3;
  const int k0i = li >> 8;
  const int col = nt * 16 + (lane & 15);
  const int kbase = k0i * 32 + (lane >> 4) * 8;
  half8 h;
#pragma unroll
  for (int j = 0; j < 8; ++j)
    h[j] = (_Float16)(W[(size_t)(kbase + j) * D_OUT + col] * scale);
  reinterpret_cast<half8*>(bfrag)[idx] = h;
}

// ---------------------------------------------------------------------------
// Kernel A: H = X @ W + b via mfma_f32_16x16x32_f16.
// One wave = 16 rows x 64 cols (4 col-tiles x 4 K-steps = 16 MFMAs).
// C/D: col = lane&15 (+nt*16), row = r0 + (lane>>4)*4 + r   [m89 mapping]
// which==0 -> fp16 hk (pre-scaled by sqrt(log2e)); which==1 -> bf16 hv.
// ---------------------------------------------------------------------------
__global__ __launch_bounds__(256) void linear_mfma_kernel(
    const float* __restrict__ Xk, const float* __restrict__ Xv,
    const float* __restrict__ Wk, const float* __restrict__ bk,
    const float* __restrict__ Wv, const float* __restrict__ bv,
    const _Float16* __restrict__ bfrag, unsigned short* __restrict__ hkv,
    int R, int nblk) {
  const int which = (blockIdx.x >= nblk) ? 1 : 0;
  const int blk = blockIdx.x - which * nblk;
  const float* __restrict__ X = which ? Xv : Xk;
  const float* __restrict__ bias = which ? bv : bk;
  const float bscale = which ? 1.0f : SQRT_LOG2E;
  const int uoff = which ? D_OUT : 0;

  const int wave = threadIdx.x >> 6;
  const int lane = threadIdx.x & 63;
  const int r0 = (blk * 4 + wave) * 16;
  if (r0 >= R) return;
  const int rowi = lane & 15;
  const int kgrp = lane >> 4;

  if (r0 + 16 <= R) {
    const half8* btab =
        reinterpret_cast<const half8*>(bfrag) + (which ? 1024 : 0);
    half8 bf[4][4];
#pragma unroll
    for (int k0i = 0; k0i < 4; ++k0i)
#pragma unroll
      for (int nt = 0; nt < 4; ++nt)
        bf[k0i][nt] = btab[(k0i * 4 + nt) * 64 + lane];

    f32x4 acc[4];
#pragma unroll
    for (int nt = 0; nt < 4; ++nt) acc[nt] = (f32x4){0.f, 0.f, 0.f, 0.f};

    const float* xrow = X + (size_t)(r0 + rowi) * D_IN;
#pragma unroll
    for (int k0i = 0; k0i < 4; ++k0i) {
      const float4 x0 =
          *reinterpret_cast<const float4*>(xrow + k0i * 32 + kgrp * 8);
      const float4 x1 =
          *reinterpret_cast<const float4*>(xrow + k0i * 32 + kgrp * 8 + 4);
      half8 a;
      a[0] = (_Float16)x0.x; a[1] = (_Float16)x0.y;
      a[2] = (_Float16)x0.z; a[3] = (_Float16)x0.w;
      a[4] = (_Float16)x1.x; a[5] = (_Float16)x1.y;
      a[6] = (_Float16)x1.z; a[7] = (_Float16)x1.w;
#pragma unroll
      for (int nt = 0; nt < 4; ++nt)
        acc[nt] = __builtin_amdgcn_mfma_f32_16x16x32_f16(a, bf[k0i][nt],
                                                         acc[nt], 0, 0, 0);
    }
#pragma unroll
    for (int nt = 0; nt < 4; ++nt) {
      const int col = nt * 16 + rowi;
      const float bcol = bias[col] * bscale;
#pragma unroll
      for (int r = 0; r < 4; ++r) {
        const int row = r0 + kgrp * 4 + r;
        const float val = acc[nt][r] + bcol;
        hkv[(size_t)row * ROWH + uoff + col] =
            which ? f2bf(val) : f2h(val);
      }
    }
  } else {
    // tail rows (R%16 != 0 only): direct f32 dot, lane = column
    const float* __restrict__ W = which ? Wv : Wk;
    for (int r = r0; r < R; ++r) {
      const float* xr = X + (size_t)r * D_IN;
      float acc = bias[lane];
      for (int k = 0; k < D_IN; ++k)
        acc = fmaf(xr[k], W[(size_t)k * D_OUT + lane], acc);
      acc *= bscale;
      hkv[(size_t)r * ROWH + uoff + lane] = which ? f2bf(acc) : f2h(acc);
    }
  }
}

// ---------------------------------------------------------------------------
// Kernel B: CSR row pointers from sorted dst. row_ptr[i] = lower_bound(dst, i)
// ---------------------------------------------------------------------------
__global__ void rowptr_kernel(const int* __restrict__ dst, int E, int N,
                              int* __restrict__ row_ptr) {
  int i = blockIdx.x * blockDim.x + threadIdx.x;
  if (i > N) return;
  int lo = 0, hi = E;
  while (lo < hi) {
    int mid = (lo + hi) >> 1;
    if (dst[mid] < i) lo = mid + 1; else hi = mid;
  }
  row_ptr[i] = lo;
}

// ---------------------------------------------------------------------------
// sum over each 16-lane row via DPP rotate-adds (pure VALU).
// ---------------------------------------------------------------------------
__device__ __forceinline__ float rowsum16(float p) {
  union { float f; int i; } u, v;
  u.f = p;
  v.i = __builtin_amdgcn_update_dpp(0, u.i, 0x121, 0xF, 0xF, true);  // row_ror:1
  u.f += v.f;
  v.i = __builtin_amdgcn_update_dpp(0, u.i, 0x122, 0xF, 0xF, true);  // row_ror:2
  u.f += v.f;
  v.i = __builtin_amdgcn_update_dpp(0, u.i, 0x124, 0xF, 0xF, true);  // row_ror:4
  u.f += v.f;
  v.i = __builtin_amdgcn_update_dpp(0, u.i, 0x128, 0xF, 0xF, true);  // row_ror:8
  u.f += v.f;
  return u.f;
}

// ---------------------------------------------------------------------------
// Kernel C: chunked two-phase segmented softmax aggregation.
// Wave = 2 nodes x 2 batches; group of 16 lanes owns one (node,batch) segment
// -> no cross-group merges. Per chunk of 8 edges: pass 1 gathers k-lines and
// computes 8 independent dots (regs, static idx) + chunk max; ONE branchless
// rescale; pass 2 gathers v-lines and exp2-weighted accumulates.
// hk fp16 pre-scaled to exp2 domain; hv bf16; 256 B rows.
// ---------------------------------------------------------------------------
__global__ __launch_bounds__(256) void aggregate_kernel(
    const unsigned short* __restrict__ hkv, const int* __restrict__ src,
    const int* __restrict__ row_ptr, float* __restrict__ out, int N) {
  const int wid = blockIdx.x * 4 + (threadIdx.x >> 6);
  const int lane = threadIdx.x & 63;
  const int g = lane >> 4;       // group: bit0 = batch, bit1 = node select
  const int li = lane & 15;      // dim-quad index (uint2 granule)
  const int node = wid * 2 + (g >> 1);
  const int batch = g & 1;
  if (node >= N) return;

  const unsigned short* hb = hkv + (size_t)batch * N * ROWH;
  const uint2* myrow = reinterpret_cast<const uint2*>(hb + (size_t)node * ROWH);
  const uint2 kd = myrow[li];
  const int e0 = row_ptr[node];
  const int e1 = row_ptr[node + 1];

  float m = -FLT_MAX, l = 0.f;
  float4 acc = {0.f, 0.f, 0.f, 0.f};

  for (int ec = e0; ec < e1; ec += 8) {
    // ---- pass 1: k-line gathers + dots + chunk max ----
    int sidx[8];
    float p[8];
    float cmax = -FLT_MAX;
#pragma unroll
    for (int i = 0; i < 8; ++i) {
      if (ec + i < e1) {
        sidx[i] = src[ec + i];
        const uint2 ks =
            reinterpret_cast<const uint2*>(hb + (size_t)sidx[i] * ROWH)[li];
        p[i] = rowsum16(hdot4(ks, kd));
        cmax = fmaxf(cmax, p[i]);
      }
    }
    // ---- one branchless rescale per chunk ----
    const float mn = fmaxf(m, cmax);
    const float sc = exp2f(m - mn);  // first chunk: exp2(-inf) = 0
    l *= sc;
    acc.x *= sc; acc.y *= sc; acc.z *= sc; acc.w *= sc;
    m = mn;
    // ---- pass 2: v-line gathers + weighted accumulate ----
#pragma unroll
    for (int i = 0; i < 8; ++i) {
      if (ec + i < e1) {
        const uint2 vu =
            reinterpret_cast<const uint2*>(hb + (size_t)sidx[i] * ROWH)[16 + li];
        const float a = exp2f(p[i] - m);
        const float4 vs = unpack_bf4(vu);
        l += a;
        acc.x = fmaf(a, vs.x, acc.x);
        acc.y = fmaf(a, vs.y, acc.y);
        acc.z = fmaf(a, vs.z, acc.z);
        acc.w = fmaf(a, vs.w, acc.w);
      }
    }
  }

  const float denom = (l == 0.f) ? 1.f : l;
  float4 o;
  o.x = acc.x / denom; o.y = acc.y / denom;
  o.z = acc.z / denom; o.w = acc.w / denom;
  o.x = (o.x >= 0.f) ? o.x : NEG_SLOPE * o.x;
  o.y = (o.y >= 0.f) ? o.y : NEG_SLOPE * o.y;
  o.z = (o.z >= 0.f) ? o.z : NEG_SLOPE * o.z;
  o.w = (o.w >= 0.f) ? o.w : NEG_SLOPE * o.w;
  *reinterpret_cast<float4*>(out + ((size_t)batch * N + node) * D_OUT + 4 * li) = o;
}

// ---------------------------------------------------------------------------
extern "C" void kernel_launch(void* const* d_in, const int* in_sizes, int n_in,
                              void* d_out, int out_size, void* d_ws,
                              size_t ws_size, hipStream_t stream) {
  const float* X_key   = (const float*)d_in[0];
  const float* X_value = (const float*)d_in[1];
  const float* Wk      = (const float*)d_in[2];
  const float* bk      = (const float*)d_in[3];
  const float* Wv      = (const float*)d_in[4];
  const float* bv      = (const float*)d_in[5];
  const int*   src     = (const int*)d_in[6];
  const int*   dst     = (const int*)d_in[7];
  float* out = (float*)d_out;

  const int B = 2;
  const int R = in_sizes[0] / D_IN;  // B*N rows
  const int N = R / B;
  const int E = in_sizes[6];

  // workspace: bfrag 32KB (16B-aligned) | hkv ushort[R][128] | row_ptr
  _Float16* bfrag = (_Float16*)d_ws;
  unsigned short* hkv = (unsigned short*)((char*)d_ws + 32768);
  int* row_ptr = (int*)(hkv + (size_t)R * ROWH);

  const int blocksB = (N + 1 + 255) / 256;
  hipLaunchKernelGGL(rowptr_kernel, dim3(blocksB), dim3(256), 0, stream,
                     dst, E, N, row_ptr);
  hipLaunchKernelGGL(bfrag_kernel, dim3(8), dim3(256), 0, stream,
                     Wk, Wv, bfrag);
  const int wavesPerMat = (R + 15) / 16;
  const int nblk = (wavesPerMat + 3) / 4;
  hipLaunchKernelGGL(linear_mfma_kernel, dim3(2 * nblk), dim3(256), 0, stream,
                     X_key, X_value, Wk, bk, Wv, bv, bfrag, hkv, R, nblk);
  const int blocksC = (N + 7) / 8;  // wave = 2 nodes x 2 batches
  hipLaunchKernelGGL(aggregate_kernel, dim3(blocksC), dim3(256), 0, stream,
                     hkv, src, row_ptr, out, N);
}

// Round 13
// 115.662 us; speedup vs baseline: 1.0998x; 1.0998x over previous
//
#include <hip/hip_runtime.h>
#include <cfloat>
#include <math.h>

#define D_IN 128
#define D_OUT 64
#define NEG_SLOPE 0.2f
#define ROWH 128  // ushorts per hkv row: 16 granules of [4 fp16 k | 4 fp16 v]
#define SQRT_LOG2E 1.2011224087864498f
#define DEFER_THR 8.0f

typedef _Float16 half2v __attribute__((ext_vector_type(2)));
typedef _Float16 half8 __attribute__((ext_vector_type(8)));
typedef float f32x4 __attribute__((ext_vector_type(4)));

// helpers ---------------------------------------------------------------------
__device__ __forceinline__ unsigned short f2h(float x) {
  union { _Float16 h; unsigned short u; } c;
  c.h = (_Float16)x;  // RNE
  return c.u;
}
// fp16-pair dot with f32 accumulate via v_dot2_f32_f16
__device__ __forceinline__ float hdot4(unsigned ax, unsigned ay,
                                       unsigned bx, unsigned by) {
  union { unsigned u; half2v h; } al, ah, bl, bh;
  al.u = ax; ah.u = ay; bl.u = bx; bh.u = by;
#if __has_builtin(__builtin_amdgcn_fdot2)
  return __builtin_amdgcn_fdot2(al.h, bl.h,
         __builtin_amdgcn_fdot2(ah.h, bh.h, 0.f, false), false);
#else
  return (float)al.h[0] * (float)bl.h[0] + (float)al.h[1] * (float)bl.h[1] +
         (float)ah.h[0] * (float)bh.h[0] + (float)ah.h[1] * (float)bh.h[1];
#endif
}

// ---------------------------------------------------------------------------
// Kernel P: pack W (f32) into per-lane MFMA B-fragments (fp16).
// Wk pre-scaled by sqrt(log2 e) so gathered score dots land in exp2 domain.
// idx < 1024: Wk table; idx >= 1024: Wv table. 2048 entries x 16 B = 32 KB.
// ---------------------------------------------------------------------------
__global__ void bfrag_kernel(const float* __restrict__ Wk,
                             const float* __restrict__ Wv,
                             _Float16* __restrict__ bfrag) {
  const int idx = blockIdx.x * 256 + threadIdx.x;
  if (idx >= 2048) return;
  const int which = idx >> 10;
  const float* __restrict__ W = which ? Wv : Wk;
  const float scale = which ? 1.0f : SQRT_LOG2E;
  const int li = idx & 1023;
  const int lane = li & 63;
  const int nt = (li >> 6) & 3;
  const int k0i = li >> 8;
  const int col = nt * 16 + (lane & 15);
  const int kbase = k0i * 32 + (lane >> 4) * 8;
  half8 h;
#pragma unroll
  for (int j = 0; j < 8; ++j)
    h[j] = (_Float16)(W[(size_t)(kbase + j) * D_OUT + col] * scale);
  reinterpret_cast<half8*>(bfrag)[idx] = h;
}

// ---------------------------------------------------------------------------
// Kernel A: H = X @ W + b via mfma_f32_16x16x32_f16.
// One wave = 16 rows x 64 cols (4 col-tiles x 4 K-steps = 16 MFMAs).
// C/D: col = lane&15 (+nt*16), row = r0 + (lane>>4)*4 + r   [m89 mapping]
// Output row layout: granule g holds k[4g..4g+3] then v[4g..4g+3] (all fp16).
// which==0 -> k at ushort 8*(c>>2)+(c&3) (pre-scaled); which==1 -> v at +4.
// ---------------------------------------------------------------------------
__global__ __launch_bounds__(256) void linear_mfma_kernel(
    const float* __restrict__ Xk, const float* __restrict__ Xv,
    const float* __restrict__ Wk, const float* __restrict__ bk,
    const float* __restrict__ Wv, const float* __restrict__ bv,
    const _Float16* __restrict__ bfrag, unsigned short* __restrict__ hkv,
    int R, int nblk) {
  const int which = (blockIdx.x >= nblk) ? 1 : 0;
  const int blk = blockIdx.x - which * nblk;
  const float* __restrict__ X = which ? Xv : Xk;
  const float* __restrict__ bias = which ? bv : bk;
  const float bscale = which ? 1.0f : SQRT_LOG2E;
  const int voff = which ? 4 : 0;

  const int wave = threadIdx.x >> 6;
  const int lane = threadIdx.x & 63;
  const int r0 = (blk * 4 + wave) * 16;
  if (r0 >= R) return;
  const int rowi = lane & 15;
  const int kgrp = lane >> 4;

  if (r0 + 16 <= R) {
    const half8* btab =
        reinterpret_cast<const half8*>(bfrag) + (which ? 1024 : 0);
    half8 bf[4][4];
#pragma unroll
    for (int k0i = 0; k0i < 4; ++k0i)
#pragma unroll
      for (int nt = 0; nt < 4; ++nt)
        bf[k0i][nt] = btab[(k0i * 4 + nt) * 64 + lane];

    f32x4 acc[4];
#pragma unroll
    for (int nt = 0; nt < 4; ++nt) acc[nt] = (f32x4){0.f, 0.f, 0.f, 0.f};

    const float* xrow = X + (size_t)(r0 + rowi) * D_IN;
#pragma unroll
    for (int k0i = 0; k0i < 4; ++k0i) {
      const float4 x0 =
          *reinterpret_cast<const float4*>(xrow + k0i * 32 + kgrp * 8);
      const float4 x1 =
          *reinterpret_cast<const float4*>(xrow + k0i * 32 + kgrp * 8 + 4);
      half8 a;
      a[0] = (_Float16)x0.x; a[1] = (_Float16)x0.y;
      a[2] = (_Float16)x0.z; a[3] = (_Float16)x0.w;
      a[4] = (_Float16)x1.x; a[5] = (_Float16)x1.y;
      a[6] = (_Float16)x1.z; a[7] = (_Float16)x1.w;
#pragma unroll
      for (int nt = 0; nt < 4; ++nt)
        acc[nt] = __builtin_amdgcn_mfma_f32_16x16x32_f16(a, bf[k0i][nt],
                                                         acc[nt], 0, 0, 0);
    }
#pragma unroll
    for (int nt = 0; nt < 4; ++nt) {
      const int col = nt * 16 + rowi;
      const int uidx = 8 * (col >> 2) + (col & 3) + voff;
      const float bcol = bias[col] * bscale;
#pragma unroll
      for (int r = 0; r < 4; ++r) {
        const int row = r0 + kgrp * 4 + r;
        hkv[(size_t)row * ROWH + uidx] = f2h(acc[nt][r] + bcol);
      }
    }
  } else {
    // tail rows (R%16 != 0 only): direct f32 dot, lane = column
    const float* __restrict__ W = which ? Wv : Wk;
    const int uidx = 8 * (lane >> 2) + (lane & 3) + voff;
    for (int r = r0; r < R; ++r) {
      const float* xr = X + (size_t)r * D_IN;
      float acc = bias[lane];
      for (int k = 0; k < D_IN; ++k)
        acc = fmaf(xr[k], W[(size_t)k * D_OUT + lane], acc);
      acc *= bscale;
      hkv[(size_t)r * ROWH + uidx] = f2h(acc);
    }
  }
}

// ---------------------------------------------------------------------------
// Kernel B: CSR row pointers from sorted dst. row_ptr[i] = lower_bound(dst, i)
// ---------------------------------------------------------------------------
__global__ void rowptr_kernel(const int* __restrict__ dst, int E, int N,
                              int* __restrict__ row_ptr) {
  int i = blockIdx.x * blockDim.x + threadIdx.x;
  if (i > N) return;
  int lo = 0, hi = E;
  while (lo < hi) {
    int mid = (lo + hi) >> 1;
    if (dst[mid] < i) lo = mid + 1; else hi = mid;
  }
  row_ptr[i] = lo;
}

// ---------------------------------------------------------------------------
// sum over each 16-lane row via DPP rotate-adds (pure VALU).
// ---------------------------------------------------------------------------
__device__ __forceinline__ float rowsum16(float p) {
  union { float f; int i; } u, v;
  u.f = p;
  v.i = __builtin_amdgcn_update_dpp(0, u.i, 0x121, 0xF, 0xF, true);  // row_ror:1
  u.f += v.f;
  v.i = __builtin_amdgcn_update_dpp(0, u.i, 0x122, 0xF, 0xF, true);  // row_ror:2
  u.f += v.f;
  v.i = __builtin_amdgcn_update_dpp(0, u.i, 0x124, 0xF, 0xF, true);  // row_ror:4
  u.f += v.f;
  v.i = __builtin_amdgcn_update_dpp(0, u.i, 0x128, 0xF, 0xF, true);  // row_ror:8
  u.f += v.f;
  return u.f;
}

// online-softmax state, exp2 domain, defer-max (weights bounded by 2^THR)
struct SMState { float m, l; float4 a; };

__device__ __forceinline__ void sm_update(SMState& st, float pl,
                                          const uint2& vu) {
  if (pl > st.m + DEFER_THR) {  // rare: ~2% of visits
    const float sc = exp2f(st.m - pl);  // first edge: exp2(-inf) = 0
    st.l *= sc;
    st.a.x *= sc; st.a.y *= sc; st.a.z *= sc; st.a.w *= sc;
    st.m = pl;
  }
  const float a = exp2f(pl - st.m);
  union { unsigned u; half2v h; } vlo, vhi;
  vlo.u = vu.x; vhi.u = vu.y;
  st.l += a;
  st.a.x = fmaf(a, (float)vlo.h[0], st.a.x);  // v_fma_mix_f32
  st.a.y = fmaf(a, (float)vlo.h[1], st.a.y);
  st.a.z = fmaf(a, (float)vhi.h[0], st.a.z);
  st.a.w = fmaf(a, (float)vhi.h[1], st.a.w);
}

__device__ __forceinline__ void sm_merge(SMState& d, const SMState& s) {
  const float mn = fmaxf(d.m, s.m);
  const float s1 = exp2f(d.m - mn);
  const float s2 = exp2f(s.m - mn);
  d.l = d.l * s1 + s.l * s2;
  d.a.x = d.a.x * s1 + s.a.x * s2;
  d.a.y = d.a.y * s1 + s.a.y * s2;
  d.a.z = d.a.z * s1 + s.a.z * s2;
  d.a.w = d.a.w * s1 + s.a.w * s2;
  d.m = mn;
}

__device__ __forceinline__ void sm_merge_xor(SMState& d, int off) {
  SMState s;
  s.m = __shfl_xor(d.m, off, 64);
  s.l = __shfl_xor(d.l, off, 64);
  s.a.x = __shfl_xor(d.a.x, off, 64);
  s.a.y = __shfl_xor(d.a.y, off, 64);
  s.a.z = __shfl_xor(d.a.z, off, 64);
  s.a.w = __shfl_xor(d.a.w, off, 64);
  sm_merge(d, s);
}

// one edge-visit: ONE uint4 load (16 B granule = k-quad + v-quad)
__device__ __forceinline__ void edge_proc(const unsigned short* __restrict__ hb,
                                          int s, int li, const uint2& kd,
                                          SMState& st) {
  const uint4 q = reinterpret_cast<const uint4*>(hb + (size_t)s * ROWH)[li];
  const float pl = rowsum16(hdot4(q.x, q.y, kd.x, kd.y));
  sm_update(st, pl, (uint2){q.z, q.w});
}

// ---------------------------------------------------------------------------
// Kernel C: per-node segmented online-softmax aggregation, BOTH batches per
// wave (R11 structure). 4 groups of 16 lanes; per group 2 ILP states x 2
// batches = 4 chains. Interleaved kv granules: 1 load/visit; fp16 k (exp2
// pre-scaled) + fp16 v (fma_mix); defer-max rescale.
// ---------------------------------------------------------------------------
__global__ __launch_bounds__(256) void aggregate_kernel(
    const unsigned short* __restrict__ hkv, const int* __restrict__ src,
    const int* __restrict__ row_ptr, float* __restrict__ out, int N) {
  const int node = blockIdx.x * 4 + (threadIdx.x >> 6);
  const int lane = threadIdx.x & 63;
  if (node >= N) return;
  const unsigned short* hb0 = hkv;
  const unsigned short* hb1 = hkv + (size_t)N * ROWH;

  const int li = lane & 15;  // granule index (16 B each)
  const int g = lane >> 4;   // edge group

  const uint4 kq0 = reinterpret_cast<const uint4*>(hb0 + (size_t)node * ROWH)[li];
  const uint4 kq1 = reinterpret_cast<const uint4*>(hb1 + (size_t)node * ROWH)[li];
  const uint2 kd0 = {kq0.x, kq0.y};
  const uint2 kd1 = {kq1.x, kq1.y};
  const int e0 = row_ptr[node];
  const int e1 = row_ptr[node + 1];

  SMState A0 = {-FLT_MAX, 0.f, {0.f, 0.f, 0.f, 0.f}};
  SMState B0 = A0, A1 = A0, B1 = A0;

  int e = e0 + g;
  for (; e + 4 < e1; e += 8) {
    const int sA = src[e];
    const int sB = src[e + 4];
    edge_proc(hb0, sA, li, kd0, A0);
    edge_proc(hb1, sA, li, kd1, A1);
    edge_proc(hb0, sB, li, kd0, B0);
    edge_proc(hb1, sB, li, kd1, B1);
  }
  if (e < e1) {
    const int sA = src[e];
    edge_proc(hb0, sA, li, kd0, A0);
    edge_proc(hb1, sA, li, kd1, A1);
  }

  sm_merge(A0, B0);
  sm_merge(A1, B1);
  sm_merge_xor(A0, 16); sm_merge_xor(A0, 32);
  sm_merge_xor(A1, 16); sm_merge_xor(A1, 32);

  if (lane < 16) {
#pragma unroll
    for (int b = 0; b < 2; ++b) {
      const SMState& S = b ? A1 : A0;
      const float denom = (S.l == 0.f) ? 1.f : S.l;
      float4 o;
      o.x = S.a.x / denom; o.y = S.a.y / denom;
      o.z = S.a.z / denom; o.w = S.a.w / denom;
      o.x = (o.x >= 0.f) ? o.x : NEG_SLOPE * o.x;
      o.y = (o.y >= 0.f) ? o.y : NEG_SLOPE * o.y;
      o.z = (o.z >= 0.f) ? o.z : NEG_SLOPE * o.z;
      o.w = (o.w >= 0.f) ? o.w : NEG_SLOPE * o.w;
      *reinterpret_cast<float4*>(out + ((size_t)b * N + node) * D_OUT + 4 * lane) = o;
    }
  }
}

// ---------------------------------------------------------------------------
extern "C" void kernel_launch(void* const* d_in, const int* in_sizes, int n_in,
                              void* d_out, int out_size, void* d_ws,
                              size_t ws_size, hipStream_t stream) {
  const float* X_key   = (const float*)d_in[0];
  const float* X_value = (const float*)d_in[1];
  const float* Wk      = (const float*)d_in[2];
  const float* bk      = (const float*)d_in[3];
  const float* Wv      = (const float*)d_in[4];
  const float* bv      = (const float*)d_in[5];
  const int*   src     = (const int*)d_in[6];
  const int*   dst     = (const int*)d_in[7];
  float* out = (float*)d_out;

  const int B = 2;
  const int R = in_sizes[0] / D_IN;  // B*N rows
  const int N = R / B;
  const int E = in_sizes[6];

  // workspace: bfrag 32KB (16B-aligned) | hkv ushort[R][128] | row_ptr
  _Float16* bfrag = (_Float16*)d_ws;
  unsigned short* hkv = (unsigned short*)((char*)d_ws + 32768);
  int* row_ptr = (int*)(hkv + (size_t)R * ROWH);

  const int blocksB = (N + 1 + 255) / 256;
  hipLaunchKernelGGL(rowptr_kernel, dim3(blocksB), dim3(256), 0, stream,
                     dst, E, N, row_ptr);
  hipLaunchKernelGGL(bfrag_kernel, dim3(8), dim3(256), 0, stream,
                     Wk, Wv, bfrag);
  const int wavesPerMat = (R + 15) / 16;
  const int nblk = (wavesPerMat + 3) / 4;
  hipLaunchKernelGGL(linear_mfma_kernel, dim3(2 * nblk), dim3(256), 0, stream,
                     X_key, X_value, Wk, bk, Wv, bv, bfrag, hkv, R, nblk);
  const int blocksC = (N + 3) / 4;  // one wave per node, both batches
  hipLaunchKernelGGL(aggregate_kernel, dim3(blocksC), dim3(256), 0, stream,
                     hkv, src, row_ptr, out, N);
}

// Round 14
// 107.281 us; speedup vs baseline: 1.1857x; 1.0781x over previous
//
#include <hip/hip_runtime.h>
#include <cfloat>
#include <math.h>

#define D_IN 128
#define D_OUT 64
#define NEG_SLOPE 0.2f
#define ROWH 128  // ushorts per hkv row: [64 fp16 k | 64 fp16 v] = 256 B
#define SQRT_LOG2E 1.2011224087864498f
#define DEFER_THR 8.0f

typedef _Float16 half2v __attribute__((ext_vector_type(2)));
typedef _Float16 half8 __attribute__((ext_vector_type(8)));
typedef float f32x4 __attribute__((ext_vector_type(4)));

// helpers ---------------------------------------------------------------------
__device__ __forceinline__ unsigned short f2h(float x) {
  union { _Float16 h; unsigned short u; } c;
  c.h = (_Float16)x;  // RNE
  return c.u;
}
// fp16-pair dot with f32 accumulate via v_dot2_f32_f16
__device__ __forceinline__ float hdot4(unsigned ax, unsigned ay,
                                       unsigned bx, unsigned by) {
  union { unsigned u; half2v h; } al, ah, bl, bh;
  al.u = ax; ah.u = ay; bl.u = bx; bh.u = by;
#if __has_builtin(__builtin_amdgcn_fdot2)
  return __builtin_amdgcn_fdot2(al.h, bl.h,
         __builtin_amdgcn_fdot2(ah.h, bh.h, 0.f, false), false);
#else
  return (float)al.h[0] * (float)bl.h[0] + (float)al.h[1] * (float)bl.h[1] +
         (float)ah.h[0] * (float)bh.h[0] + (float)ah.h[1] * (float)bh.h[1];
#endif
}

// ---------------------------------------------------------------------------
// Kernel P: pack W (f32) into per-lane MFMA B-fragments (fp16).
// Wk pre-scaled by sqrt(log2 e) so gathered score dots land in exp2 domain.
// idx < 1024: Wk table; idx >= 1024: Wv table. 2048 entries x 16 B = 32 KB.
// ---------------------------------------------------------------------------
__global__ void bfrag_kernel(const float* __restrict__ Wk,
                             const float* __restrict__ Wv,
                             _Float16* __restrict__ bfrag) {
  const int idx = blockIdx.x * 256 + threadIdx.x;
  if (idx >= 2048) return;
  const int which = idx >> 10;
  const float* __restrict__ W = which ? Wv : Wk;
  const float scale = which ? 1.0f : SQRT_LOG2E;
  const int li = idx & 1023;
  const int lane = li & 63;
  const int nt = (li >> 6) & 3;
  const int k0i = li >> 8;
  const int col = nt * 16 + (lane & 15);
  const int kbase = k0i * 32 + (lane >> 4) * 8;
  half8 h;
#pragma unroll
  for (int j = 0; j < 8; ++j)
    h[j] = (_Float16)(W[(size_t)(kbase + j) * D_OUT + col] * scale);
  reinterpret_cast<half8*>(bfrag)[idx] = h;
}

// ---------------------------------------------------------------------------
// Kernel A: H = X @ W + b via mfma_f32_16x16x32_f16.
// One wave = 16 rows x 64 cols (4 col-tiles x 4 K-steps = 16 MFMAs).
// C/D: col = lane&15 (+nt*16), row = r0 + (lane>>4)*4 + r   [m89 mapping]
// which==0 -> fp16 k at ushort col (pre-scaled); which==1 -> fp16 v at 64+col.
// ---------------------------------------------------------------------------
__global__ __launch_bounds__(256) void linear_mfma_kernel(
    const float* __restrict__ Xk, const float* __restrict__ Xv,
    const float* __restrict__ Wk, const float* __restrict__ bk,
    const float* __restrict__ Wv, const float* __restrict__ bv,
    const _Float16* __restrict__ bfrag, unsigned short* __restrict__ hkv,
    int R, int nblk) {
  const int which = (blockIdx.x >= nblk) ? 1 : 0;
  const int blk = blockIdx.x - which * nblk;
  const float* __restrict__ X = which ? Xv : Xk;
  const float* __restrict__ bias = which ? bv : bk;
  const float bscale = which ? 1.0f : SQRT_LOG2E;
  const int uoff = which ? D_OUT : 0;

  const int wave = threadIdx.x >> 6;
  const int lane = threadIdx.x & 63;
  const int r0 = (blk * 4 + wave) * 16;
  if (r0 >= R) return;
  const int rowi = lane & 15;
  const int kgrp = lane >> 4;

  if (r0 + 16 <= R) {
    const half8* btab =
        reinterpret_cast<const half8*>(bfrag) + (which ? 1024 : 0);
    half8 bf[4][4];
#pragma unroll
    for (int k0i = 0; k0i < 4; ++k0i)
#pragma unroll
      for (int nt = 0; nt < 4; ++nt)
        bf[k0i][nt] = btab[(k0i * 4 + nt) * 64 + lane];

    f32x4 acc[4];
#pragma unroll
    for (int nt = 0; nt < 4; ++nt) acc[nt] = (f32x4){0.f, 0.f, 0.f, 0.f};

    const float* xrow = X + (size_t)(r0 + rowi) * D_IN;
#pragma unroll
    for (int k0i = 0; k0i < 4; ++k0i) {
      const float4 x0 =
          *reinterpret_cast<const float4*>(xrow + k0i * 32 + kgrp * 8);
      const float4 x1 =
          *reinterpret_cast<const float4*>(xrow + k0i * 32 + kgrp * 8 + 4);
      half8 a;
      a[0] = (_Float16)x0.x; a[1] = (_Float16)x0.y;
      a[2] = (_Float16)x0.z; a[3] = (_Float16)x0.w;
      a[4] = (_Float16)x1.x; a[5] = (_Float16)x1.y;
      a[6] = (_Float16)x1.z; a[7] = (_Float16)x1.w;
#pragma unroll
      for (int nt = 0; nt < 4; ++nt)
        acc[nt] = __builtin_amdgcn_mfma_f32_16x16x32_f16(a, bf[k0i][nt],
                                                         acc[nt], 0, 0, 0);
    }
#pragma unroll
    for (int nt = 0; nt < 4; ++nt) {
      const int col = nt * 16 + rowi;
      const float bcol = bias[col] * bscale;
#pragma unroll
      for (int r = 0; r < 4; ++r) {
        const int row = r0 + kgrp * 4 + r;
        hkv[(size_t)row * ROWH + uoff + col] = f2h(acc[nt][r] + bcol);
      }
    }
  } else {
    // tail rows (R%16 != 0 only): direct f32 dot, lane = column
    const float* __restrict__ W = which ? Wv : Wk;
    for (int r = r0; r < R; ++r) {
      const float* xr = X + (size_t)r * D_IN;
      float acc = bias[lane];
      for (int k = 0; k < D_IN; ++k)
        acc = fmaf(xr[k], W[(size_t)k * D_OUT + lane], acc);
      acc *= bscale;
      hkv[(size_t)r * ROWH + uoff + lane] = f2h(acc);
    }
  }
}

// ---------------------------------------------------------------------------
// Kernel B: CSR row pointers from sorted dst. row_ptr[i] = lower_bound(dst, i)
// ---------------------------------------------------------------------------
__global__ void rowptr_kernel(const int* __restrict__ dst, int E, int N,
                              int* __restrict__ row_ptr) {
  int i = blockIdx.x * blockDim.x + threadIdx.x;
  if (i > N) return;
  int lo = 0, hi = E;
  while (lo < hi) {
    int mid = (lo + hi) >> 1;
    if (dst[mid] < i) lo = mid + 1; else hi = mid;
  }
  row_ptr[i] = lo;
}

// ---------------------------------------------------------------------------
// sum over each 16-lane row via DPP rotate-adds (pure VALU).
// ---------------------------------------------------------------------------
__device__ __forceinline__ float rowsum16(float p) {
  union { float f; int i; } u, v;
  u.f = p;
  v.i = __builtin_amdgcn_update_dpp(0, u.i, 0x121, 0xF, 0xF, true);  // row_ror:1
  u.f += v.f;
  v.i = __builtin_amdgcn_update_dpp(0, u.i, 0x122, 0xF, 0xF, true);  // row_ror:2
  u.f += v.f;
  v.i = __builtin_amdgcn_update_dpp(0, u.i, 0x124, 0xF, 0xF, true);  // row_ror:4
  u.f += v.f;
  v.i = __builtin_amdgcn_update_dpp(0, u.i, 0x128, 0xF, 0xF, true);  // row_ror:8
  u.f += v.f;
  return u.f;
}

// online-softmax state, exp2 domain, defer-max (weights bounded by 2^THR)
struct SMState { float m, l; float4 a; };

__device__ __forceinline__ void sm_update(SMState& st, float pl,
                                          const uint2& vu) {
  if (pl > st.m + DEFER_THR) {  // rare: ~2% of visits
    const float sc = exp2f(st.m - pl);  // first edge: exp2(-inf) = 0
    st.l *= sc;
    st.a.x *= sc; st.a.y *= sc; st.a.z *= sc; st.a.w *= sc;
    st.m = pl;
  }
  const float a = exp2f(pl - st.m);
  union { unsigned u; half2v h; } vlo, vhi;
  vlo.u = vu.x; vhi.u = vu.y;
  st.l += a;
  st.a.x = fmaf(a, (float)vlo.h[0], st.a.x);  // v_fma_mix_f32
  st.a.y = fmaf(a, (float)vlo.h[1], st.a.y);
  st.a.z = fmaf(a, (float)vhi.h[0], st.a.z);
  st.a.w = fmaf(a, (float)vhi.h[1], st.a.w);
}

__device__ __forceinline__ void sm_merge(SMState& d, const SMState& s) {
  const float mn = fmaxf(d.m, s.m);
  const float s1 = exp2f(d.m - mn);
  const float s2 = exp2f(s.m - mn);
  d.l = d.l * s1 + s.l * s2;
  d.a.x = d.a.x * s1 + s.a.x * s2;
  d.a.y = d.a.y * s1 + s.a.y * s2;
  d.a.z = d.a.z * s1 + s.a.z * s2;
  d.a.w = d.a.w * s1 + s.a.w * s2;
  d.m = mn;
}

__device__ __forceinline__ void sm_merge_xor(SMState& d, int off) {
  SMState s;
  s.m = __shfl_xor(d.m, off, 64);
  s.l = __shfl_xor(d.l, off, 64);
  s.a.x = __shfl_xor(d.a.x, off, 64);
  s.a.y = __shfl_xor(d.a.y, off, 64);
  s.a.z = __shfl_xor(d.a.z, off, 64);
  s.a.w = __shfl_xor(d.a.w, off, 64);
  sm_merge(d, s);
}

// one edge-visit: two INDEPENDENT 8 B loads (k line, v line at +128 B imm)
__device__ __forceinline__ void edge_proc(const char* __restrict__ hb,
                                          unsigned off, const uint2& kd,
                                          SMState& st) {
  const uint2 kq = *reinterpret_cast<const uint2*>(hb + off);
  const uint2 vq = *reinterpret_cast<const uint2*>(hb + off + 128);
  const float pl = rowsum16(hdot4(kq.x, kq.y, kd.x, kd.y));
  sm_update(st, pl, vq);
}

// ---------------------------------------------------------------------------
// Kernel C: per-node segmented online-softmax aggregation, BOTH batches per
// wave (R11 structure: 8 independent gathers in flight per iteration).
// 4 groups of 16 lanes; per group 2 ILP states x 2 batches = 4 chains.
// 32-bit byte-offset addressing: one v_lshl_add per edge serves 4 loads.
// fp16 k (exp2 pre-scaled) + fp16 v; defer-max rescale.
// ---------------------------------------------------------------------------
__global__ __launch_bounds__(256) void aggregate_kernel(
    const unsigned short* __restrict__ hkv, const int* __restrict__ src,
    const int* __restrict__ row_ptr, float* __restrict__ out, int N) {
  const int node = blockIdx.x * 4 + (threadIdx.x >> 6);
  const int lane = threadIdx.x & 63;
  if (node >= N) return;
  const char* hb0 = reinterpret_cast<const char*>(hkv);
  const char* hb1 = hb0 + (size_t)N * 256;

  const int li = lane & 15;      // dim-quad index
  const unsigned li8 = li * 8;   // byte offset of k-quad within row
  const int g = lane >> 4;       // edge group

  const unsigned noff = ((unsigned)node << 8) + li8;
  const uint2 kd0 = *reinterpret_cast<const uint2*>(hb0 + noff);
  const uint2 kd1 = *reinterpret_cast<const uint2*>(hb1 + noff);
  const int e0 = row_ptr[node];
  const int e1 = row_ptr[node + 1];

  SMState A0 = {-FLT_MAX, 0.f, {0.f, 0.f, 0.f, 0.f}};
  SMState B0 = A0, A1 = A0, B1 = A0;

  int e = e0 + g;
  for (; e + 4 < e1; e += 8) {
    const unsigned offA = ((unsigned)src[e] << 8) + li8;
    const unsigned offB = ((unsigned)src[e + 4] << 8) + li8;
    edge_proc(hb0, offA, kd0, A0);
    edge_proc(hb1, offA, kd1, A1);
    edge_proc(hb0, offB, kd0, B0);
    edge_proc(hb1, offB, kd1, B1);
  }
  if (e < e1) {
    const unsigned offA = ((unsigned)src[e] << 8) + li8;
    edge_proc(hb0, offA, kd0, A0);
    edge_proc(hb1, offA, kd1, A1);
  }

  sm_merge(A0, B0);
  sm_merge(A1, B1);
  sm_merge_xor(A0, 16); sm_merge_xor(A0, 32);
  sm_merge_xor(A1, 16); sm_merge_xor(A1, 32);

  if (lane < 16) {
#pragma unroll
    for (int b = 0; b < 2; ++b) {
      const SMState& S = b ? A1 : A0;
      const float denom = (S.l == 0.f) ? 1.f : S.l;
      float4 o;
      o.x = S.a.x / denom; o.y = S.a.y / denom;
      o.z = S.a.z / denom; o.w = S.a.w / denom;
      o.x = (o.x >= 0.f) ? o.x : NEG_SLOPE * o.x;
      o.y = (o.y >= 0.f) ? o.y : NEG_SLOPE * o.y;
      o.z = (o.z >= 0.f) ? o.z : NEG_SLOPE * o.z;
      o.w = (o.w >= 0.f) ? o.w : NEG_SLOPE * o.w;
      *reinterpret_cast<float4*>(out + ((size_t)b * N + node) * D_OUT + 4 * lane) = o;
    }
  }
}

// ---------------------------------------------------------------------------
extern "C" void kernel_launch(void* const* d_in, const int* in_sizes, int n_in,
                              void* d_out, int out_size, void* d_ws,
                              size_t ws_size, hipStream_t stream) {
  const float* X_key   = (const float*)d_in[0];
  const float* X_value = (const float*)d_in[1];
  const float* Wk      = (const float*)d_in[2];
  const float* bk      = (const float*)d_in[3];
  const float* Wv      = (const float*)d_in[4];
  const float* bv      = (const float*)d_in[5];
  const int*   src     = (const int*)d_in[6];
  const int*   dst     = (const int*)d_in[7];
  float* out = (float*)d_out;

  const int B = 2;
  const int R = in_sizes[0] / D_IN;  // B*N rows
  const int N = R / B;
  const int E = in_sizes[6];

  // workspace: bfrag 32KB (16B-aligned) | hkv ushort[R][128] | row_ptr
  _Float16* bfrag = (_Float16*)d_ws;
  unsigned short* hkv = (unsigned short*)((char*)d_ws + 32768);
  int* row_ptr = (int*)(hkv + (size_t)R * ROWH);

  const int blocksB = (N + 1 + 255) / 256;
  hipLaunchKernelGGL(rowptr_kernel, dim3(blocksB), dim3(256), 0, stream,
                     dst, E, N, row_ptr);
  hipLaunchKernelGGL(bfrag_kernel, dim3(8), dim3(256), 0, stream,
                     Wk, Wv, bfrag);
  const int wavesPerMat = (R + 15) / 16;
  const int nblk = (wavesPerMat + 3) / 4;
  hipLaunchKernelGGL(linear_mfma_kernel, dim3(2 * nblk), dim3(256), 0, stream,
                     X_key, X_value, Wk, bk, Wv, bv, bfrag, hkv, R, nblk);
  const int blocksC = (N + 3) / 4;  // one wave per node, both batches
  hipLaunchKernelGGL(aggregate_kernel, dim3(blocksC), dim3(256), 0, stream,
                     hkv, src, row_ptr, out, N);
}